// Round 9
// baseline (273.854 us; speedup 1.0000x reference)
//
#include <hip/hip_runtime.h>
#include <hip/hip_bf16.h>
#include <stdint.h>

typedef unsigned short u16;
typedef __attribute__((ext_vector_type(8))) short bf16x8;
typedef __attribute__((ext_vector_type(4))) float f32x4;

#define NN 8192
#define HH 256
#define KK 100
#define BB 32
#define LL 128
#define NPAD 1024
#define SPLITK 8
#define KCH (NN / SPLITK)   // 1024
#define BK1 32
#define STEPS1 (KCH / BK1)  // 32
#define STEPS2 (512 / 64)   // 8

__device__ __forceinline__ u16 f2bf_rne(float x) {
  union { __hip_bfloat16 h; u16 u; } v;
  v.h = __float2bfloat16(x);
  return v.u;
}

__device__ __forceinline__ bf16x8 pack8(f32x4 a, f32x4 b) {
  bf16x8 r;
  r[0] = (short)f2bf_rne(a.x); r[1] = (short)f2bf_rne(a.y);
  r[2] = (short)f2bf_rne(a.z); r[3] = (short)f2bf_rne(a.w);
  r[4] = (short)f2bf_rne(b.x); r[5] = (short)f2bf_rne(b.y);
  r[6] = (short)f2bf_rne(b.z); r[7] = (short)f2bf_rne(b.w);
  return r;
}

// async global->LDS, 16B/lane. LDS dest wave-uniform; HW adds lane*16.
__device__ __forceinline__ void gld16(const void* g, void* l) {
  __builtin_amdgcn_global_load_lds(
      (const __attribute__((address_space(1))) unsigned int*)g,
      (__attribute__((address_space(3))) unsigned int*)l, 16, 0, 0);
}

// ---------------------------------------------------------------- embT: [256][8192] bf16 = emb^T
__global__ __launch_bounds__(256) void convert_embT(const float* __restrict__ emb,
                                                    u16* __restrict__ embT) {
  __shared__ float t[64][65];
  const int tid = threadIdx.x;
  const int k0 = blockIdx.x * 64, n0 = blockIdx.y * 64;
#pragma unroll
  for (int i = 0; i < 16; ++i) {
    int idx = i * 256 + tid;
    int r = idx >> 6, c = idx & 63;
    t[r][c] = emb[(size_t)(k0 + r) * HH + n0 + c];
  }
  __syncthreads();
#pragma unroll
  for (int i = 0; i < 16; ++i) {
    int idx = i * 256 + tid;
    int r = idx >> 6, c = idx & 63;
    embT[(size_t)(n0 + r) * NN + k0 + c] = f2bf_rne(t[c][r]);
  }
}

// ---------------------------------------------------------------- layer1 = adj @ emb (bf16 MFMA)
// T3/T4 3-deep: BK=32, 3 LDS buffers, counted vmcnt(6/3/0), raw barriers.
// BM=64, BN=256, splitK=8. Grid 1024 flat (sk=wg&7 -> per-XCD embT slice). 2 blocks/CU.
__global__ __launch_bounds__(512, 4) void gemm_layer1(const float* __restrict__ adj,
                                                      const u16* __restrict__ embT,
                                                      float* __restrict__ parts) {
  __shared__ __align__(16) float As[3][64 * 32];   // 8 KB x3, 16B-granule swizzle ^(row&7)
  __shared__ __align__(16) u16 Bs[3][256 * 32];    // 16 KB x3, granule swizzle ^((row>>1)&3)
  const int tid = threadIdx.x;
  const int lane = tid & 63, wid = tid >> 6;
  const int wm = wid >> 2, wn = wid & 3;
  const int wg = blockIdx.x;
  const int sk = wg & 7;
  const int m0 = (wg >> 3) * 64;
  const int kbeg = sk * KCH;

  f32x4 acc[2][4];
  const f32x4 zf = {0.f, 0.f, 0.f, 0.f};
#pragma unroll
  for (int i = 0; i < 2; ++i)
#pragma unroll
    for (int j = 0; j < 4; ++j) acc[i][j] = zf;

  // A staging: one 1KB instr per wave: 8 rows x 32 f32. lane -> row=wid*8+(lane>>3), gran=(lane&7)
  const int aRow = wid * 8 + (lane >> 3);
  const int aGsrc = (lane & 7) ^ (aRow & 7);               // pre-swizzled source granule
  const float* aSrc = adj + (size_t)(m0 + aRow) * NN + kbeg + aGsrc * 4;
  // B staging: two 1KB instrs per wave: t=wid*2+j, 16 rows x 32 bf16. lane -> row=t*16+(lane>>2), gran=lane&3
  const int bRow0 = wid * 32 + (lane >> 2);                // t = wid*2
  const int bRow1 = bRow0 + 16;                            // t = wid*2+1
  const int bG0 = (lane & 3) ^ ((bRow0 >> 1) & 3);
  const int bG1 = (lane & 3) ^ ((bRow1 >> 1) & 3);
  const u16* bSrc0 = embT + (size_t)bRow0 * NN + kbeg + bG0 * 8;
  const u16* bSrc1 = embT + (size_t)bRow1 * NN + kbeg + bG1 * 8;

  auto ISSUE = [&](int s, int buf) {
    const int ks = s * BK1;
    gld16(aSrc + ks, (void*)&As[buf][wid * 256]);
    gld16(bSrc0 + ks, (void*)&Bs[buf][(wid * 2) * 512]);
    gld16(bSrc1 + ks, (void*)&Bs[buf][(wid * 2 + 1) * 512]);
  };
  auto COMPUTE = [&](int buf) {
    bf16x8 af[2], bfr[4];
    const int g0 = (lane >> 4) * 2;          // A granule pair
#pragma unroll
    for (int mi = 0; mi < 2; ++mi) {
      int row = wm * 32 + mi * 16 + (lane & 15);
      f32x4 p0 = *reinterpret_cast<const f32x4*>(&As[buf][row * 32 + ((g0 ^ (row & 7)) << 2)]);
      f32x4 p1 = *reinterpret_cast<const f32x4*>(&As[buf][row * 32 + (((g0 + 1) ^ (row & 7)) << 2)]);
      af[mi] = pack8(p0, p1);
    }
#pragma unroll
    for (int ni = 0; ni < 4; ++ni) {
      int row = wn * 64 + ni * 16 + (lane & 15);
      int el = ((lane >> 4) ^ ((row >> 1) & 3)) << 3;
      bfr[ni] = *reinterpret_cast<const bf16x8*>(&Bs[buf][row * 32 + el]);
    }
#pragma unroll
    for (int mi = 0; mi < 2; ++mi)
#pragma unroll
      for (int ni = 0; ni < 4; ++ni)
        acc[mi][ni] = __builtin_amdgcn_mfma_f32_16x16x32_bf16(af[mi], bfr[ni], acc[mi][ni], 0, 0, 0);
  };

  ISSUE(0, 0);
  ISSUE(1, 1);
  int ib = 2, cb = 0;
  for (int s = 0; s < STEPS1; ++s) {
    if (s + 2 < STEPS1) {
      ISSUE(s + 2, ib);
      asm volatile("s_waitcnt vmcnt(6)" ::: "memory");   // step-s landed; s+1,s+2 in flight
    } else if (s + 1 < STEPS1) {
      asm volatile("s_waitcnt vmcnt(3)" ::: "memory");
    } else {
      asm volatile("s_waitcnt vmcnt(0)" ::: "memory");
    }
    __builtin_amdgcn_s_barrier();
    COMPUTE(cb);
    __builtin_amdgcn_s_barrier();
    ib = (ib == 2) ? 0 : ib + 1;
    cb = (cb == 2) ? 0 : cb + 1;
  }

  float* outp = parts + (size_t)sk * ((size_t)NN * HH);
  const int r0 = (lane >> 4) << 2;
  const int coln = wn * 64 + (lane & 15);
#pragma unroll
  for (int mi = 0; mi < 2; ++mi)
#pragma unroll
    for (int ni = 0; ni < 4; ++ni)
#pragma unroll
      for (int r = 0; r < 4; ++r)
        outp[(size_t)(m0 + wm * 32 + mi * 16 + r0 + r) * HH + coln + ni * 16] = acc[mi][ni][r];
}

// ---------------------------------------------------------------- gather: Q/A rows = sum of split-K parts
__global__ __launch_bounds__(256) void gather_qa(const float* __restrict__ parts,
                                                 const int* __restrict__ q_idx,
                                                 const int* __restrict__ a_idx,
                                                 float* __restrict__ Q, float* __restrict__ A) {
  const int rb = blockIdx.x;
  const bool isA = rb >= BB * LL;
  const int r = isA ? rb - BB * LL : rb;
  const int idx = (isA ? a_idx : q_idx)[r];
  const int tid = threadIdx.x;
  float s = 0.f;
#pragma unroll
  for (int p = 0; p < SPLITK; ++p)
    s += parts[(size_t)p * ((size_t)NN * HH) + (size_t)idx * HH + tid];
  (isA ? A : Q)[(size_t)r * HH + tid] = s;
}

// ---------------------------------------------------------------- score + row softmax fused
__global__ __launch_bounds__(128) void score_row(const float* __restrict__ Q,
                                                 const float* __restrict__ A,
                                                 float* __restrict__ score,
                                                 float* __restrict__ wq) {
  __shared__ float qs[HH];
  __shared__ float red[4];
  const int bl = blockIdx.x;
  const int b = bl >> 7;
  const int tid = threadIdx.x;
  const int wv = tid >> 6, lane = tid & 63;
  qs[tid] = Q[(size_t)bl * HH + tid];
  qs[tid + 128] = Q[(size_t)bl * HH + tid + 128];
  __syncthreads();
  const float4* a4 = reinterpret_cast<const float4*>(A + ((size_t)b * LL + tid) * HH);
  const float4* q4 = reinterpret_cast<const float4*>(qs);
  float acc = 0.f;
#pragma unroll 8
  for (int h = 0; h < HH / 4; ++h) {
    float4 av = a4[h], qv = q4[h];
    acc += av.x * qv.x + av.y * qv.y + av.z * qv.z + av.w * qv.w;
  }
  float mx = acc;
#pragma unroll
  for (int off = 32; off; off >>= 1) mx = fmaxf(mx, __shfl_xor(mx, off));
  if (lane == 0) red[wv] = mx;
  __syncthreads();
  mx = fmaxf(red[0], red[1]);
  float e = expf(acc - mx);
  float sm = e;
#pragma unroll
  for (int off = 32; off; off >>= 1) sm += __shfl_xor(sm, off);
  if (lane == 0) red[2 + wv] = sm;
  __syncthreads();
  sm = red[2] + red[3];
  score[(size_t)bl * LL + tid] = acc;
  wq[(size_t)bl * LL + tid] = e / sm;
}

// ---------------------------------------------------------------- col softmax via LDS-staged per-b tile
__global__ __launch_bounds__(256) void softmax_colB(const float* __restrict__ score,
                                                    float* __restrict__ waT) {
  __shared__ float sc[128 * 132];
  const int b = blockIdx.x;
  const int tid = threadIdx.x;
  const float4* src = reinterpret_cast<const float4*>(score + (size_t)b * LL * LL);
#pragma unroll
  for (int i = 0; i < 16; ++i) {
    int f4i = i * 256 + tid;
    int l = f4i >> 5, m4 = f4i & 31;
    *reinterpret_cast<float4*>(&sc[l * 132 + m4 * 4]) = src[f4i];
  }
  __syncthreads();
  if (tid < 128) {
    const int m = tid;
    float mx = -3.4e38f;
    for (int l = 0; l < 128; ++l) mx = fmaxf(mx, sc[l * 132 + m]);
    float sum = 0.f;
    for (int l = 0; l < 128; ++l) {
      float e = expf(sc[l * 132 + m] - mx);
      sc[l * 132 + m] = e;
      sum += e;
    }
    float inv = 1.f / sum;
    for (int l = 0; l < 128; ++l) sc[l * 132 + m] *= inv;
  }
  __syncthreads();
  float* dst = waT + (size_t)b * LL * LL;
#pragma unroll
  for (int i = 0; i < 64; ++i) {
    int idx = i * 256 + tid;
    int m = idx >> 7, l = idx & 127;
    dst[idx] = sc[l * 132 + m];
  }
}

// ---------------------------------------------------------------- align+encode: EQ/EA + match features -> Tbf
__global__ __launch_bounds__(1024) void align_encode(const float* __restrict__ wq,
                                                     const float* __restrict__ waT,
                                                     const float* __restrict__ Q,
                                                     const float* __restrict__ A,
                                                     u16* __restrict__ Tbf) {
  __shared__ float wl[128 * 128];
  __shared__ float sl[128 * 64];
  const int bid = blockIdx.x;
  const int side = bid >> 7;
  const int b = (bid >> 2) & 31;
  const int h0 = (bid & 3) * 64;
  const int tid = threadIdx.x;
  const int lt = tid >> 6, hx = tid & 63;

  const float* wsrc = (side ? waT : wq) + (size_t)b * (LL * LL);
  const float* ssrc = (side ? Q : A) + (size_t)b * (LL * HH) + h0;
  const float* msrc = (side ? A : Q) + (size_t)b * (LL * HH) + h0;

#pragma unroll
  for (int i = 0; i < 16; ++i) {
    int idx = i * 1024 + tid;
    wl[idx] = wsrc[idx];
  }
#pragma unroll
  for (int i = 0; i < 8; ++i) {
    int idx = i * 1024 + tid;
    int r = idx >> 6, c = idx & 63;
    sl[idx] = ssrc[(size_t)r * HH + c];
  }
  __syncthreads();

  float accv[8];
#pragma unroll
  for (int ii = 0; ii < 8; ++ii) accv[ii] = 0.f;

  for (int j4 = 0; j4 < 128; j4 += 4) {
    float s0 = sl[(j4 + 0) * 64 + hx];
    float s1 = sl[(j4 + 1) * 64 + hx];
    float s2 = sl[(j4 + 2) * 64 + hx];
    float s3 = sl[(j4 + 3) * 64 + hx];
#pragma unroll
    for (int ii = 0; ii < 8; ++ii) {
      float4 wv = *reinterpret_cast<const float4*>(&wl[(lt + 16 * ii) * 128 + j4]);
      accv[ii] += wv.x * s0 + wv.y * s1 + wv.z * s2 + wv.w * s3;
    }
  }

  u16* outp = Tbf + (size_t)(side * 4096 + b * 128) * 512 + h0;
#pragma unroll
  for (int ii = 0; ii < 8; ++ii) {
    int i = lt + 16 * ii;
    float mv = msrc[(size_t)i * HH + hx];
    float e = accv[ii];
    float d = mv - e;
    outp[(size_t)i * 512 + hx] = f2bf_rne(d * d);
    outp[(size_t)i * 512 + 256 + hx] = f2bf_rne(mv * e);
  }
}

// ---------------------------------------------------------------- Wcat bf16 [1024][512]
__global__ __launch_bounds__(256) void prep_wcat(const float* __restrict__ w0,
                                                 const float* __restrict__ w1,
                                                 const float* __restrict__ w2,
                                                 const float* __restrict__ w3,
                                                 u16* __restrict__ Wcat) {
  const int kr = blockIdx.x;
  const int tid = threadIdx.x;
  u16* out = Wcat + (size_t)kr * 512;
  if (kr >= KK * 10) {
    out[tid] = 0;
    out[tid + 256] = 0;
    return;
  }
  const int k = kr / 10, s = kr % 10;
  const float* w;
  int r, fs;
  if (s < 1)      { w = w0; r = s;     fs = 1; }
  else if (s < 3) { w = w1; r = s - 1; fs = 2; }
  else if (s < 6) { w = w2; r = s - 3; fs = 3; }
  else            { w = w3; r = s - 6; fs = 4; }
  const float* src = w + ((size_t)k * fs + r) * 522 + 5;
  out[tid] = f2bf_rne(src[tid]);
  out[tid + 256] = f2bf_rne(src[tid + 256]);
}

// ---------------------------------------------------------------- conv GEMM: D[8192][1024] = Tbf @ Wcat^T (R6 version)
__global__ __launch_bounds__(512, 4) void gemm_conv(const u16* __restrict__ Tbf,
                                                    const u16* __restrict__ Wcat,
                                                    float* __restrict__ D) {
  __shared__ __align__(16) u16 As[128 * 64];   // 16 KB
  __shared__ __align__(16) u16 Bs[256 * 64];   // 32 KB
  const int tid = threadIdx.x;
  const int lane = tid & 63, wid = tid >> 6;
  const int wm = wid >> 2, wn = wid & 3;
  const int m0 = blockIdx.x * 128;
  const int n0 = blockIdx.y * 256;

  f32x4 acc[4][4];
  const f32x4 zf = {0.f, 0.f, 0.f, 0.f};
#pragma unroll
  for (int i = 0; i < 4; ++i)
#pragma unroll
    for (int j = 0; j < 4; ++j) acc[i][j] = zf;

  const int browL = (lane >> 3);
  const int bkL = (lane & 7) << 3;

  for (int s = 0; s < STEPS2; ++s) {
    const int ks = s * 64;
#pragma unroll
    for (int j = 0; j < 2; ++j) {
      int rowA = (wid << 4) + (j << 3) + browL;
      int kA = bkL ^ ((rowA & 7) << 3);
      gld16(Tbf + (size_t)(m0 + rowA) * 512 + ks + kA, (void*)&As[(wid * 2 + j) * 512]);
    }
#pragma unroll
    for (int j = 0; j < 4; ++j) {
      int rowB = (wid << 5) + (j << 3) + browL;
      int kB = bkL ^ ((rowB & 7) << 3);
      gld16(Wcat + (size_t)(n0 + rowB) * 512 + ks + kB, (void*)&Bs[(wid * 4 + j) * 512]);
    }
    __syncthreads();
#pragma unroll
    for (int kk = 0; kk < 64; kk += 32) {
      const int krow = kk + ((lane >> 4) << 3);
      bf16x8 af[4], bfr[4];
#pragma unroll
      for (int mi = 0; mi < 4; ++mi) {
        int row = wm * 64 + mi * 16 + (lane & 15);
        af[mi] = *reinterpret_cast<const bf16x8*>(&As[row * 64 + (krow ^ ((row & 7) << 3))]);
      }
#pragma unroll
      for (int ni = 0; ni < 4; ++ni) {
        int row = wn * 64 + ni * 16 + (lane & 15);
        bfr[ni] = *reinterpret_cast<const bf16x8*>(&Bs[row * 64 + (krow ^ ((row & 7) << 3))]);
      }
#pragma unroll
      for (int mi = 0; mi < 4; ++mi)
#pragma unroll
        for (int ni = 0; ni < 4; ++ni)
          acc[mi][ni] = __builtin_amdgcn_mfma_f32_16x16x32_bf16(af[mi], bfr[ni], acc[mi][ni], 0, 0, 0);
    }
    __syncthreads();
  }

  const int r0 = (lane >> 4) << 2;
  const int coln = n0 + wn * 64 + (lane & 15);
#pragma unroll
  for (int mi = 0; mi < 4; ++mi)
#pragma unroll
    for (int ni = 0; ni < 4; ++ni)
#pragma unroll
      for (int r = 0; r < 4; ++r)
        D[(size_t)(m0 + wm * 64 + mi * 16 + r0 + r) * NPAD + coln + ni * 16] = acc[mi][ni][r];
}

// ---------------------------------------------------------------- shift-sum + bias + relu + maxpool -> re[32][800]
__global__ __launch_bounds__(256) void reduce_conv(const float* __restrict__ D,
                                                   const float* __restrict__ b0,
                                                   const float* __restrict__ b1,
                                                   const float* __restrict__ b2,
                                                   const float* __restrict__ b3,
                                                   float* __restrict__ re) {
  __shared__ float tile[128][101];
  const int pair = blockIdx.y;
  const int sel = pair >> 5, b = pair & 31;
  const int kc = blockIdx.x;
  const int tid = threadIdx.x;
  const int rowbase = sel * (BB * LL) + b * LL;
  const int c0 = kc * 100;
  for (int idx = tid; idx < 12800; idx += 256) {
    int r = idx / 100, c = idx - r * 100;
    tile[r][c] = D[(size_t)(rowbase + r) * NPAD + c0 + c];
  }
  __syncthreads();
  const int wid = tid >> 6, lane = tid & 63;
  const int offt[4] = {0, 1, 3, 6};
  const int fst[4] = {1, 2, 3, 4};
  for (int o = wid; o < 40; o += 4) {
    const int kk = o >> 2, f = o & 3;
    const int fs = fst[f], off = offt[f];
    const int kg = kc * 10 + kk;
    const float bias = (f == 0 ? b0 : f == 1 ? b1 : f == 2 ? b2 : b3)[kg];
    const int col = kk * 10 + off;
    const int outh = 139 - fs;
    float best = 0.f;
    for (int i = lane; i < outh; i += 64) {
      float s = bias;
#pragma unroll 4
      for (int r = 0; r < 4; ++r) {
        if (r < fs) {
          int j = i + r - 5;
          if (j >= 0 && j < LL) s += tile[j][col + r];
        }
      }
      best = fmaxf(best, s);
    }
    best = fmaxf(best, 0.f);
#pragma unroll
    for (int d = 32; d; d >>= 1) best = fmaxf(best, __shfl_xor(best, d));
    if (lane == 0) re[(size_t)b * 800 + sel * 400 + f * 100 + kg] = best;
  }
}

// ---------------------------------------------------------------- dense + log_softmax -> out[32][2]
__global__ __launch_bounds__(64) void dense_logsm(const float* __restrict__ re,
                                                  const float* __restrict__ dw,
                                                  const float* __restrict__ db,
                                                  float* __restrict__ out) {
  const int b = blockIdx.x;
  const int lane = threadIdx.x;
  const float* r = re + (size_t)b * 800;
  float a0 = 0.f, a1 = 0.f;
  for (int j = lane; j < 800; j += 64) {
    float rv = r[j];
    a0 += rv * dw[j * 2];
    a1 += rv * dw[j * 2 + 1];
  }
#pragma unroll
  for (int d = 32; d; d >>= 1) {
    a0 += __shfl_xor(a0, d);
    a1 += __shfl_xor(a1, d);
  }
  if (lane == 0) {
    a0 += db[0];
    a1 += db[1];
    float mx = fmaxf(a0, a1);
    float lse = mx + logf(expf(a0 - mx) + expf(a1 - mx));
    out[b * 2] = a0 - lse;
    out[b * 2 + 1] = a1 - lse;
  }
}

// ---------------------------------------------------------------- workspace layout (bytes)
static const size_t OFF_PARTS = 0;                         // 8 * 8192*256 f32 = 67,108,864
static const size_t OFF_D     = 0;                         // alias (parts dead by conv time)
static const size_t OFF_Q     = 67108864;
static const size_t OFF_A     = OFF_Q + 4194304;
static const size_t OFF_SCORE = OFF_A + 4194304;
static const size_t OFF_WQ    = OFF_SCORE + 2097152;
static const size_t OFF_WAT   = OFF_WQ + 2097152;
static const size_t OFF_RE    = OFF_WAT + 2097152;
static const size_t OFF_TBF   = OFF_RE + 102400;
static const size_t OFF_WCAT  = OFF_TBF + 8388608;
static const size_t OFF_EMBT  = OFF_WCAT + 1048576;

extern "C" void kernel_launch(void* const* d_in, const int* in_sizes, int n_in,
                              void* d_out, int out_size, void* d_ws, size_t ws_size,
                              hipStream_t stream) {
  (void)in_sizes; (void)n_in; (void)out_size; (void)ws_size;
  const float* adj  = (const float*)d_in[0];
  const float* emb  = (const float*)d_in[1];
  const int* q_idx  = (const int*)d_in[2];
  const int* a_idx  = (const int*)d_in[3];
  const float* cw0 = (const float*)d_in[4];
  const float* cb0 = (const float*)d_in[5];
  const float* cw1 = (const float*)d_in[6];
  const float* cb1 = (const float*)d_in[7];
  const float* cw2 = (const float*)d_in[8];
  const float* cb2 = (const float*)d_in[9];
  const float* cw3 = (const float*)d_in[10];
  const float* cb3 = (const float*)d_in[11];
  const float* dw = (const float*)d_in[12];
  const float* db = (const float*)d_in[13];
  float* out = (float*)d_out;

  char* ws = (char*)d_ws;
  float* parts = (float*)(ws + OFF_PARTS);
  float* Dbuf  = (float*)(ws + OFF_D);
  float* Q     = (float*)(ws + OFF_Q);
  float* Abuf  = (float*)(ws + OFF_A);
  float* score = (float*)(ws + OFF_SCORE);
  float* wq    = (float*)(ws + OFF_WQ);
  float* waT   = (float*)(ws + OFF_WAT);
  float* re    = (float*)(ws + OFF_RE);
  u16* Tbf     = (u16*)(ws + OFF_TBF);
  u16* Wcat    = (u16*)(ws + OFF_WCAT);
  u16* embT    = (u16*)(ws + OFF_EMBT);

  convert_embT<<<dim3(128, 4), 256, 0, stream>>>(emb, embT);
  prep_wcat<<<1024, 256, 0, stream>>>(cw0, cw1, cw2, cw3, Wcat);
  gemm_layer1<<<128 * SPLITK, 512, 0, stream>>>(adj, embT, parts);
  gather_qa<<<2 * BB * LL, 256, 0, stream>>>(parts, q_idx, a_idx, Q, Abuf);
  score_row<<<BB * LL, 128, 0, stream>>>(Q, Abuf, score, wq);
  softmax_colB<<<BB, 256, 0, stream>>>(score, waT);
  align_encode<<<256, 1024, 0, stream>>>(wq, waT, Q, Abuf, Tbf);
  gemm_conv<<<dim3(64, 4), 512, 0, stream>>>(Tbf, Wcat, Dbuf);
  reduce_conv<<<dim3(10, 64), 256, 0, stream>>>(Dbuf, cb0, cb1, cb2, cb3, re);
  dense_logsm<<<BB, 64, 0, stream>>>(re, dw, db, out);
}

// Round 10
// 217.271 us; speedup vs baseline: 1.2604x; 1.2604x over previous
//
#include <hip/hip_runtime.h>
#include <hip/hip_bf16.h>
#include <stdint.h>

typedef unsigned short u16;
typedef __attribute__((ext_vector_type(8))) short bf16x8;
typedef __attribute__((ext_vector_type(4))) float f32x4;

#define NN 8192
#define HH 256
#define KK 100
#define BB 32
#define LL 128
#define NPAD 1024
#define SPLITK 8
#define KCH (NN / SPLITK)   // 1024
#define STEPS1 (KCH / 64)   // 16
#define STEPS2 (512 / 64)   // 8

__device__ __forceinline__ u16 f2bf_rne(float x) {
  union { __hip_bfloat16 h; u16 u; } v;
  v.h = __float2bfloat16(x);
  return v.u;
}

__device__ __forceinline__ bf16x8 pack8(f32x4 a, f32x4 b) {
  bf16x8 r;
  r[0] = (short)f2bf_rne(a.x); r[1] = (short)f2bf_rne(a.y);
  r[2] = (short)f2bf_rne(a.z); r[3] = (short)f2bf_rne(a.w);
  r[4] = (short)f2bf_rne(b.x); r[5] = (short)f2bf_rne(b.y);
  r[6] = (short)f2bf_rne(b.z); r[7] = (short)f2bf_rne(b.w);
  return r;
}

// async global->LDS, 16B/lane. LDS dest wave-uniform; HW adds lane*16. Global src is per-lane.
__device__ __forceinline__ void gld16(const void* g, void* l) {
  __builtin_amdgcn_global_load_lds(
      (const __attribute__((address_space(1))) unsigned int*)g,
      (__attribute__((address_space(3))) unsigned int*)l, 16, 0, 0);
}

// ---------------------------------------------------------------- embT: [256][8192] bf16 = emb^T
__global__ __launch_bounds__(256) void convert_embT(const float* __restrict__ emb,
                                                    u16* __restrict__ embT) {
  __shared__ float t[64][65];
  const int tid = threadIdx.x;
  const int k0 = blockIdx.x * 64, n0 = blockIdx.y * 64;
#pragma unroll
  for (int i = 0; i < 16; ++i) {
    int idx = i * 256 + tid;
    int r = idx >> 6, c = idx & 63;
    t[r][c] = emb[(size_t)(k0 + r) * HH + n0 + c];
  }
  __syncthreads();
#pragma unroll
  for (int i = 0; i < 16; ++i) {
    int idx = i * 256 + tid;
    int r = idx >> 6, c = idx & 63;
    embT[(size_t)(n0 + r) * NN + k0 + c] = f2bf_rne(t[c][r]);
  }
}

// ---------------------------------------------------------------- dedup: bitmap + scan over 8192 rows
// one block, 1024 threads. rank[n], rows[] (compact, +64 zero pad), muniq.
__global__ __launch_bounds__(1024) void dedup_rows(const int* __restrict__ q_idx,
                                                   const int* __restrict__ a_idx,
                                                   int* __restrict__ rank,
                                                   int* __restrict__ rows,
                                                   int* __restrict__ muniq) {
  __shared__ unsigned bm[256];
  __shared__ int cnt[1024];
  __shared__ int total;
  const int tid = threadIdx.x;
  if (tid < 256) bm[tid] = 0u;
  __syncthreads();
  for (int i = tid; i < BB * LL; i += 1024) {
    int q = q_idx[i];
    atomicOr(&bm[q >> 5], 1u << (q & 31));
  }
  for (int i = tid; i < BB * LL; i += 1024) {
    int a = a_idx[i];
    atomicOr(&bm[a >> 5], 1u << (a & 31));
  }
  __syncthreads();
  const unsigned w = bm[tid >> 2];
  const unsigned byte = (w >> ((tid & 3) * 8)) & 0xffu;
  const int myc = __popc(byte);
  cnt[tid] = myc;
  __syncthreads();
  for (int off = 1; off < 1024; off <<= 1) {
    int v = (tid >= off) ? cnt[tid - off] : 0;
    __syncthreads();
    cnt[tid] += v;
    __syncthreads();
  }
  if (tid == 1023) total = cnt[1023];
  int base = cnt[tid] - myc;
#pragma unroll
  for (int j = 0; j < 8; ++j) {
    int n = tid * 8 + j;
    int bit = (byte >> j) & 1;
    rank[n] = base;
    if (bit) rows[base++] = n;
  }
  __syncthreads();
  if (tid == 0) *muniq = total;
  if (tid < 64) rows[total + tid] = 0;
}

// ---------------------------------------------------------------- layer1 compact: C = adj[rows] @ emb (bf16 MFMA)
// BM=64, BN=256, BK=64, splitK=8. grid 1024 flat (sk=wg&7, mt=wg>>3), early-exit mt>=tiles.
// 48 KB LDS -> 3 blocks/CU. m97 structure (gld16 + syncthreads).
__global__ __launch_bounds__(512, 6) void gemm_layer1c(const float* __restrict__ adj,
                                                       const u16* __restrict__ embT,
                                                       const int* __restrict__ rows,
                                                       const int* __restrict__ muniq,
                                                       float* __restrict__ parts) {
  __shared__ __align__(16) float As[64 * 64];  // 16 KB, 16-granule swizzle ^(row&15)
  __shared__ __align__(16) u16 Bs[256 * 64];   // 32 KB, 8-granule swizzle ^(row&7)
  const int tid = threadIdx.x;
  const int lane = tid & 63, wid = tid >> 6;
  const int wm = wid >> 2, wn = wid & 3;
  const int wg = blockIdx.x;
  const int sk = wg & 7;
  const int mt = wg >> 3;
  const int m0 = mt * 64;
  const int M = *muniq;
  if (m0 >= M) return;
  const int kbeg = sk * KCH;

  f32x4 acc[2][4];
  const f32x4 zf = {0.f, 0.f, 0.f, 0.f};
#pragma unroll
  for (int i = 0; i < 2; ++i)
#pragma unroll
    for (int j = 0; j < 4; ++j) acc[i][j] = zf;

  // A staging: 16 instrs (2/wave). instr t: 4 rows x 16 granules(16B). lane: row=t*4+(lane>>4), g=lane&15
  int aRowLoc[2], aGsrc[2];
  const float* aSrc[2];
#pragma unroll
  for (int j = 0; j < 2; ++j) {
    int t = wid * 2 + j;
    aRowLoc[j] = t * 4 + (lane >> 4);
    aGsrc[j] = (lane & 15) ^ (aRowLoc[j] & 15);
    int grow = rows[m0 + aRowLoc[j]];           // compact -> original adj row (sorted)
    aSrc[j] = adj + (size_t)grow * NN + kbeg + aGsrc[j] * 4;
  }
  // B staging: 32 instrs (4/wave). instr t: 8 rows x 8 granules. lane: row=t*8+(lane>>3), g=lane&7
  const u16* bSrc[4];
#pragma unroll
  for (int j = 0; j < 4; ++j) {
    int t = wid * 4 + j;
    int rowB = t * 8 + (lane >> 3);
    int g = (lane & 7) ^ (rowB & 7);
    bSrc[j] = embT + (size_t)rowB * NN + kbeg + g * 8;
  }

  for (int s = 0; s < STEPS1; ++s) {
    const int ks = s * 64;
#pragma unroll
    for (int j = 0; j < 2; ++j)
      gld16(aSrc[j] + ks, (void*)&As[(wid * 2 + j) * 256]);
#pragma unroll
    for (int j = 0; j < 4; ++j)
      gld16(bSrc[j] + ks, (void*)&Bs[(wid * 4 + j) * 512]);
    __syncthreads();
#pragma unroll
    for (int kk = 0; kk < 64; kk += 32) {
      bf16x8 af[2], bfr[4];
      const int g0 = (kk >> 2) + ((lane >> 4) << 1);
#pragma unroll
      for (int mi = 0; mi < 2; ++mi) {
        int row = wm * 32 + mi * 16 + (lane & 15);
        f32x4 p0 = *reinterpret_cast<const f32x4*>(&As[row * 64 + ((g0 ^ (row & 15)) << 2)]);
        f32x4 p1 = *reinterpret_cast<const f32x4*>(&As[row * 64 + (((g0 + 1) ^ (row & 15)) << 2)]);
        af[mi] = pack8(p0, p1);
      }
      const int gb = (kk >> 3) + (lane >> 4);
#pragma unroll
      for (int ni = 0; ni < 4; ++ni) {
        int row = wn * 64 + ni * 16 + (lane & 15);
        bfr[ni] = *reinterpret_cast<const bf16x8*>(&Bs[row * 64 + ((gb ^ (row & 7)) << 3)]);
      }
#pragma unroll
      for (int mi = 0; mi < 2; ++mi)
#pragma unroll
        for (int ni = 0; ni < 4; ++ni)
          acc[mi][ni] = __builtin_amdgcn_mfma_f32_16x16x32_bf16(af[mi], bfr[ni], acc[mi][ni], 0, 0, 0);
    }
    __syncthreads();
  }

  float* outp = parts + (size_t)sk * ((size_t)NN * HH);
  const int r0 = (lane >> 4) << 2;
  const int coln = wn * 64 + (lane & 15);
#pragma unroll
  for (int mi = 0; mi < 2; ++mi)
#pragma unroll
    for (int ni = 0; ni < 4; ++ni)
#pragma unroll
      for (int r = 0; r < 4; ++r)
        outp[(size_t)(m0 + wm * 32 + mi * 16 + r0 + r) * HH + coln + ni * 16] = acc[mi][ni][r];
}

// ---------------------------------------------------------------- gather: Q/A rows = sum of split-K parts (compact via rank)
__global__ __launch_bounds__(256) void gather_qa(const float* __restrict__ parts,
                                                 const int* __restrict__ q_idx,
                                                 const int* __restrict__ a_idx,
                                                 const int* __restrict__ rank,
                                                 float* __restrict__ Q, float* __restrict__ A) {
  const int rb = blockIdx.x;
  const bool isA = rb >= BB * LL;
  const int r = isA ? rb - BB * LL : rb;
  const int idx = (isA ? a_idx : q_idx)[r];
  const int cidx = rank[idx];
  const int tid = threadIdx.x;
  float s = 0.f;
#pragma unroll
  for (int p = 0; p < SPLITK; ++p)
    s += parts[(size_t)p * ((size_t)NN * HH) + (size_t)cidx * HH + tid];
  (isA ? A : Q)[(size_t)r * HH + tid] = s;
}

// ---------------------------------------------------------------- score + row softmax fused
__global__ __launch_bounds__(128) void score_row(const float* __restrict__ Q,
                                                 const float* __restrict__ A,
                                                 float* __restrict__ score,
                                                 float* __restrict__ wq) {
  __shared__ float qs[HH];
  __shared__ float red[4];
  const int bl = blockIdx.x;
  const int b = bl >> 7;
  const int tid = threadIdx.x;
  const int wv = tid >> 6, lane = tid & 63;
  qs[tid] = Q[(size_t)bl * HH + tid];
  qs[tid + 128] = Q[(size_t)bl * HH + tid + 128];
  __syncthreads();
  const float4* a4 = reinterpret_cast<const float4*>(A + ((size_t)b * LL + tid) * HH);
  const float4* q4 = reinterpret_cast<const float4*>(qs);
  float acc = 0.f;
#pragma unroll 8
  for (int h = 0; h < HH / 4; ++h) {
    float4 av = a4[h], qv = q4[h];
    acc += av.x * qv.x + av.y * qv.y + av.z * qv.z + av.w * qv.w;
  }
  float mx = acc;
#pragma unroll
  for (int off = 32; off; off >>= 1) mx = fmaxf(mx, __shfl_xor(mx, off));
  if (lane == 0) red[wv] = mx;
  __syncthreads();
  mx = fmaxf(red[0], red[1]);
  float e = expf(acc - mx);
  float sm = e;
#pragma unroll
  for (int off = 32; off; off >>= 1) sm += __shfl_xor(sm, off);
  if (lane == 0) red[2 + wv] = sm;
  __syncthreads();
  sm = red[2] + red[3];
  score[(size_t)bl * LL + tid] = acc;
  wq[(size_t)bl * LL + tid] = e / sm;
}

// ---------------------------------------------------------------- col softmax, grid (32,4): 32 cols/block
__global__ __launch_bounds__(256) void softmax_col4(const float* __restrict__ score,
                                                    float* __restrict__ waT) {
  __shared__ float tile[128 * 33];
  const int b = blockIdx.x;
  const int mg = blockIdx.y;        // column group
  const int m0 = mg * 32;
  const int tid = threadIdx.x;
  const float* src = score + (size_t)b * LL * LL + m0;
#pragma unroll
  for (int i = 0; i < 16; ++i) {
    int idx = i * 256 + tid;        // 4096 = 128 l x 32 m
    int l = idx >> 5, m = idx & 31;
    tile[l * 33 + m] = src[(size_t)l * LL + m];
  }
  __syncthreads();
  if (tid < 32) {
    const int m = tid;
    float mx = -3.4e38f;
    for (int l = 0; l < 128; ++l) mx = fmaxf(mx, tile[l * 33 + m]);
    float sum = 0.f;
    for (int l = 0; l < 128; ++l) {
      float e = expf(tile[l * 33 + m] - mx);
      tile[l * 33 + m] = e;
      sum += e;
    }
    float inv = 1.f / sum;
    for (int l = 0; l < 128; ++l) tile[l * 33 + m] *= inv;
  }
  __syncthreads();
  float* dst = waT + (size_t)b * LL * LL + (size_t)m0 * LL;
#pragma unroll
  for (int i = 0; i < 16; ++i) {
    int idx = i * 256 + tid;        // out flat = m*128 + l
    int m = idx >> 7, l = idx & 127;
    dst[idx] = tile[l * 33 + m];
  }
}

// ---------------------------------------------------------------- align+encode: EQ/EA + match features -> Tbf
__global__ __launch_bounds__(1024) void align_encode(const float* __restrict__ wq,
                                                     const float* __restrict__ waT,
                                                     const float* __restrict__ Q,
                                                     const float* __restrict__ A,
                                                     u16* __restrict__ Tbf) {
  __shared__ float wl[128 * 128];
  __shared__ float sl[128 * 64];
  const int bid = blockIdx.x;
  const int side = bid >> 7;
  const int b = (bid >> 2) & 31;
  const int h0 = (bid & 3) * 64;
  const int tid = threadIdx.x;
  const int lt = tid >> 6, hx = tid & 63;

  const float* wsrc = (side ? waT : wq) + (size_t)b * (LL * LL);
  const float* ssrc = (side ? Q : A) + (size_t)b * (LL * HH) + h0;
  const float* msrc = (side ? A : Q) + (size_t)b * (LL * HH) + h0;

#pragma unroll
  for (int i = 0; i < 16; ++i) {
    int idx = i * 1024 + tid;
    wl[idx] = wsrc[idx];
  }
#pragma unroll
  for (int i = 0; i < 8; ++i) {
    int idx = i * 1024 + tid;
    int r = idx >> 6, c = idx & 63;
    sl[idx] = ssrc[(size_t)r * HH + c];
  }
  __syncthreads();

  float accv[8];
#pragma unroll
  for (int ii = 0; ii < 8; ++ii) accv[ii] = 0.f;

  for (int j4 = 0; j4 < 128; j4 += 4) {
    float s0 = sl[(j4 + 0) * 64 + hx];
    float s1 = sl[(j4 + 1) * 64 + hx];
    float s2 = sl[(j4 + 2) * 64 + hx];
    float s3 = sl[(j4 + 3) * 64 + hx];
#pragma unroll
    for (int ii = 0; ii < 8; ++ii) {
      float4 wv = *reinterpret_cast<const float4*>(&wl[(lt + 16 * ii) * 128 + j4]);
      accv[ii] += wv.x * s0 + wv.y * s1 + wv.z * s2 + wv.w * s3;
    }
  }

  u16* outp = Tbf + (size_t)(side * 4096 + b * 128) * 512 + h0;
#pragma unroll
  for (int ii = 0; ii < 8; ++ii) {
    int i = lt + 16 * ii;
    float mv = msrc[(size_t)i * HH + hx];
    float e = accv[ii];
    float d = mv - e;
    outp[(size_t)i * 512 + hx] = f2bf_rne(d * d);
    outp[(size_t)i * 512 + 256 + hx] = f2bf_rne(mv * e);
  }
}

// ---------------------------------------------------------------- Wcat bf16 [1024][512]
__global__ __launch_bounds__(256) void prep_wcat(const float* __restrict__ w0,
                                                 const float* __restrict__ w1,
                                                 const float* __restrict__ w2,
                                                 const float* __restrict__ w3,
                                                 u16* __restrict__ Wcat) {
  const int kr = blockIdx.x;
  const int tid = threadIdx.x;
  u16* out = Wcat + (size_t)kr * 512;
  if (kr >= KK * 10) {
    out[tid] = 0;
    out[tid + 256] = 0;
    return;
  }
  const int k = kr / 10, s = kr % 10;
  const float* w;
  int r, fs;
  if (s < 1)      { w = w0; r = s;     fs = 1; }
  else if (s < 3) { w = w1; r = s - 1; fs = 2; }
  else if (s < 6) { w = w2; r = s - 3; fs = 3; }
  else            { w = w3; r = s - 6; fs = 4; }
  const float* src = w + ((size_t)k * fs + r) * 522 + 5;
  out[tid] = f2bf_rne(src[tid]);
  out[tid + 256] = f2bf_rne(src[tid + 256]);
}

// ---------------------------------------------------------------- conv GEMM: D[8192][1024] = Tbf @ Wcat^T (R6 version)
__global__ __launch_bounds__(512, 4) void gemm_conv(const u16* __restrict__ Tbf,
                                                    const u16* __restrict__ Wcat,
                                                    float* __restrict__ D) {
  __shared__ __align__(16) u16 As[128 * 64];   // 16 KB
  __shared__ __align__(16) u16 Bs[256 * 64];   // 32 KB
  const int tid = threadIdx.x;
  const int lane = tid & 63, wid = tid >> 6;
  const int wm = wid >> 2, wn = wid & 3;
  const int m0 = blockIdx.x * 128;
  const int n0 = blockIdx.y * 256;

  f32x4 acc[4][4];
  const f32x4 zf = {0.f, 0.f, 0.f, 0.f};
#pragma unroll
  for (int i = 0; i < 4; ++i)
#pragma unroll
    for (int j = 0; j < 4; ++j) acc[i][j] = zf;

  const int browL = (lane >> 3);
  const int bkL = (lane & 7) << 3;

  for (int s = 0; s < STEPS2; ++s) {
    const int ks = s * 64;
#pragma unroll
    for (int j = 0; j < 2; ++j) {
      int rowA = (wid << 4) + (j << 3) + browL;
      int kA = bkL ^ ((rowA & 7) << 3);
      gld16(Tbf + (size_t)(m0 + rowA) * 512 + ks + kA, (void*)&As[(wid * 2 + j) * 512]);
    }
#pragma unroll
    for (int j = 0; j < 4; ++j) {
      int rowB = (wid << 5) + (j << 3) + browL;
      int kB = bkL ^ ((rowB & 7) << 3);
      gld16(Wcat + (size_t)(n0 + rowB) * 512 + ks + kB, (void*)&Bs[(wid * 4 + j) * 512]);
    }
    __syncthreads();
#pragma unroll
    for (int kk = 0; kk < 64; kk += 32) {
      const int krow = kk + ((lane >> 4) << 3);
      bf16x8 af[4], bfr[4];
#pragma unroll
      for (int mi = 0; mi < 4; ++mi) {
        int row = wm * 64 + mi * 16 + (lane & 15);
        af[mi] = *reinterpret_cast<const bf16x8*>(&As[row * 64 + (krow ^ ((row & 7) << 3))]);
      }
#pragma unroll
      for (int ni = 0; ni < 4; ++ni) {
        int row = wn * 64 + ni * 16 + (lane & 15);
        bfr[ni] = *reinterpret_cast<const bf16x8*>(&Bs[row * 64 + (krow ^ ((row & 7) << 3))]);
      }
#pragma unroll
      for (int mi = 0; mi < 4; ++mi)
#pragma unroll
        for (int ni = 0; ni < 4; ++ni)
          acc[mi][ni] = __builtin_amdgcn_mfma_f32_16x16x32_bf16(af[mi], bfr[ni], acc[mi][ni], 0, 0, 0);
    }
    __syncthreads();
  }

  const int r0 = (lane >> 4) << 2;
  const int coln = n0 + wn * 64 + (lane & 15);
#pragma unroll
  for (int mi = 0; mi < 4; ++mi)
#pragma unroll
    for (int ni = 0; ni < 4; ++ni)
#pragma unroll
      for (int r = 0; r < 4; ++r)
        D[(size_t)(m0 + wm * 64 + mi * 16 + r0 + r) * NPAD + coln + ni * 16] = acc[mi][ni][r];
}

// ---------------------------------------------------------------- shift-sum + bias + relu + maxpool -> re[32][800]
__global__ __launch_bounds__(256) void reduce_conv(const float* __restrict__ D,
                                                   const float* __restrict__ b0,
                                                   const float* __restrict__ b1,
                                                   const float* __restrict__ b2,
                                                   const float* __restrict__ b3,
                                                   float* __restrict__ re) {
  __shared__ float tile[128][101];
  const int pair = blockIdx.y;
  const int sel = pair >> 5, b = pair & 31;
  const int kc = blockIdx.x;
  const int tid = threadIdx.x;
  const int rowbase = sel * (BB * LL) + b * LL;
  const int c0 = kc * 100;
  for (int idx = tid; idx < 12800; idx += 256) {
    int r = idx / 100, c = idx - r * 100;
    tile[r][c] = D[(size_t)(rowbase + r) * NPAD + c0 + c];
  }
  __syncthreads();
  const int wid = tid >> 6, lane = tid & 63;
  const int offt[4] = {0, 1, 3, 6};
  const int fst[4] = {1, 2, 3, 4};
  for (int o = wid; o < 40; o += 4) {
    const int kk = o >> 2, f = o & 3;
    const int fs = fst[f], off = offt[f];
    const int kg = kc * 10 + kk;
    const float bias = (f == 0 ? b0 : f == 1 ? b1 : f == 2 ? b2 : b3)[kg];
    const int col = kk * 10 + off;
    const int outh = 139 - fs;
    float best = 0.f;
    for (int i = lane; i < outh; i += 64) {
      float s = bias;
#pragma unroll 4
      for (int r = 0; r < 4; ++r) {
        if (r < fs) {
          int j = i + r - 5;
          if (j >= 0 && j < LL) s += tile[j][col + r];
        }
      }
      best = fmaxf(best, s);
    }
    best = fmaxf(best, 0.f);
#pragma unroll
    for (int d = 32; d; d >>= 1) best = fmaxf(best, __shfl_xor(best, d));
    if (lane == 0) re[(size_t)b * 800 + sel * 400 + f * 100 + kg] = best;
  }
}

// ---------------------------------------------------------------- dense + log_softmax -> out[32][2]
__global__ __launch_bounds__(64) void dense_logsm(const float* __restrict__ re,
                                                  const float* __restrict__ dw,
                                                  const float* __restrict__ db,
                                                  float* __restrict__ out) {
  const int b = blockIdx.x;
  const int lane = threadIdx.x;
  const float* r = re + (size_t)b * 800;
  float a0 = 0.f, a1 = 0.f;
  for (int j = lane; j < 800; j += 64) {
    float rv = r[j];
    a0 += rv * dw[j * 2];
    a1 += rv * dw[j * 2 + 1];
  }
#pragma unroll
  for (int d = 32; d; d >>= 1) {
    a0 += __shfl_xor(a0, d);
    a1 += __shfl_xor(a1, d);
  }
  if (lane == 0) {
    a0 += db[0];
    a1 += db[1];
    float mx = fmaxf(a0, a1);
    float lse = mx + logf(expf(a0 - mx) + expf(a1 - mx));
    out[b * 2] = a0 - lse;
    out[b * 2 + 1] = a1 - lse;
  }
}

// ---------------------------------------------------------------- workspace layout (bytes)
static const size_t OFF_PARTS = 0;                         // 8 * 8192*256 f32 = 67,108,864
static const size_t OFF_D     = 0;                         // alias (parts dead by conv time)
static const size_t OFF_Q     = 67108864;
static const size_t OFF_A     = OFF_Q + 4194304;
static const size_t OFF_SCORE = OFF_A + 4194304;
static const size_t OFF_WQ    = OFF_SCORE + 2097152;
static const size_t OFF_WAT   = OFF_WQ + 2097152;
static const size_t OFF_RE    = OFF_WAT + 2097152;
static const size_t OFF_TBF   = OFF_RE + 102400;
static const size_t OFF_WCAT  = OFF_TBF + 8388608;
static const size_t OFF_EMBT  = OFF_WCAT + 1048576;
static const size_t OFF_RANK  = OFF_EMBT + 4194304;        // 8192 int
static const size_t OFF_ROWS  = OFF_RANK + 32768;          // 8256 int
static const size_t OFF_MUNIQ = OFF_ROWS + 33024;          // 1 int

extern "C" void kernel_launch(void* const* d_in, const int* in_sizes, int n_in,
                              void* d_out, int out_size, void* d_ws, size_t ws_size,
                              hipStream_t stream) {
  (void)in_sizes; (void)n_in; (void)out_size; (void)ws_size;
  const float* adj  = (const float*)d_in[0];
  const float* emb  = (const float*)d_in[1];
  const int* q_idx  = (const int*)d_in[2];
  const int* a_idx  = (const int*)d_in[3];
  const float* cw0 = (const float*)d_in[4];
  const float* cb0 = (const float*)d_in[5];
  const float* cw1 = (const float*)d_in[6];
  const float* cb1 = (const float*)d_in[7];
  const float* cw2 = (const float*)d_in[8];
  const float* cb2 = (const float*)d_in[9];
  const float* cw3 = (const float*)d_in[10];
  const float* cb3 = (const float*)d_in[11];
  const float* dw = (const float*)d_in[12];
  const float* db = (const float*)d_in[13];
  float* out = (float*)d_out;

  char* ws = (char*)d_ws;
  float* parts = (float*)(ws + OFF_PARTS);
  float* Dbuf  = (float*)(ws + OFF_D);
  float* Q     = (float*)(ws + OFF_Q);
  float* Abuf  = (float*)(ws + OFF_A);
  float* score = (float*)(ws + OFF_SCORE);
  float* wq    = (float*)(ws + OFF_WQ);
  float* waT   = (float*)(ws + OFF_WAT);
  float* re    = (float*)(ws + OFF_RE);
  u16* Tbf     = (u16*)(ws + OFF_TBF);
  u16* Wcat    = (u16*)(ws + OFF_WCAT);
  u16* embT    = (u16*)(ws + OFF_EMBT);
  int* rank    = (int*)(ws + OFF_RANK);
  int* rows    = (int*)(ws + OFF_ROWS);
  int* muniq   = (int*)(ws + OFF_MUNIQ);

  convert_embT<<<dim3(128, 4), 256, 0, stream>>>(emb, embT);
  dedup_rows<<<1, 1024, 0, stream>>>(q_idx, a_idx, rank, rows, muniq);
  prep_wcat<<<1024, 256, 0, stream>>>(cw0, cw1, cw2, cw3, Wcat);
  gemm_layer1c<<<128 * SPLITK, 512, 0, stream>>>(adj, embT, rows, muniq, parts);
  gather_qa<<<2 * BB * LL, 256, 0, stream>>>(parts, q_idx, a_idx, rank, Q, Abuf);
  score_row<<<BB * LL, 128, 0, stream>>>(Q, Abuf, score, wq);
  softmax_col4<<<dim3(BB, 4), 256, 0, stream>>>(score, waT);
  align_encode<<<256, 1024, 0, stream>>>(wq, waT, Q, Abuf, Tbf);
  gemm_conv<<<dim3(64, 4), 512, 0, stream>>>(Tbf, Wcat, Dbuf);
  reduce_conv<<<dim3(10, 64), 256, 0, stream>>>(Dbuf, cb0, cb1, cb2, cb3, re);
  dense_logsm<<<BB, 64, 0, stream>>>(re, dw, db, out);
}

// Round 11
// 157.875 us; speedup vs baseline: 1.7346x; 1.3762x over previous
//
#include <hip/hip_runtime.h>
#include <hip/hip_bf16.h>
#include <stdint.h>

typedef unsigned short u16;
typedef __attribute__((ext_vector_type(8))) short bf16x8;
typedef __attribute__((ext_vector_type(4))) float f32x4;

#define NN 8192
#define HH 256
#define KK 100
#define BB 32
#define LL 128
#define NPAD 1024
#define SPLITK 8
#define KCH (NN / SPLITK)   // 1024
#define STEPS1 (KCH / 64)   // 16
#define STEPS2 (512 / 64)   // 8

__device__ __forceinline__ u16 f2bf_rne(float x) {
  union { __hip_bfloat16 h; u16 u; } v;
  v.h = __float2bfloat16(x);
  return v.u;
}

__device__ __forceinline__ float bf2f(u16 u) {
  union { unsigned int i; float f; } v;
  v.i = ((unsigned int)u) << 16;
  return v.f;
}

__device__ __forceinline__ bf16x8 pack8(f32x4 a, f32x4 b) {
  bf16x8 r;
  r[0] = (short)f2bf_rne(a.x); r[1] = (short)f2bf_rne(a.y);
  r[2] = (short)f2bf_rne(a.z); r[3] = (short)f2bf_rne(a.w);
  r[4] = (short)f2bf_rne(b.x); r[5] = (short)f2bf_rne(b.y);
  r[6] = (short)f2bf_rne(b.z); r[7] = (short)f2bf_rne(b.w);
  return r;
}

// async global->LDS, 16B/lane. LDS dest wave-uniform; HW adds lane*16. Global src per-lane.
__device__ __forceinline__ void gld16(const void* g, void* l) {
  __builtin_amdgcn_global_load_lds(
      (const __attribute__((address_space(1))) unsigned int*)g,
      (__attribute__((address_space(3))) unsigned int*)l, 16, 0, 0);
}

// ---------------------------------------------------------------- embT: [256][8192] bf16 = emb^T
__global__ __launch_bounds__(256) void convert_embT(const float* __restrict__ emb,
                                                    u16* __restrict__ embT) {
  __shared__ float t[64][65];
  const int tid = threadIdx.x;
  const int k0 = blockIdx.x * 64, n0 = blockIdx.y * 64;
#pragma unroll
  for (int i = 0; i < 16; ++i) {
    int idx = i * 256 + tid;
    int r = idx >> 6, c = idx & 63;
    t[r][c] = emb[(size_t)(k0 + r) * HH + n0 + c];
  }
  __syncthreads();
#pragma unroll
  for (int i = 0; i < 16; ++i) {
    int idx = i * 256 + tid;
    int r = idx >> 6, c = idx & 63;
    embT[(size_t)(n0 + r) * NN + k0 + c] = f2bf_rne(t[c][r]);
  }
}

// ---------------------------------------------------------------- dedup: bitmap + scan over 8192 rows
__global__ __launch_bounds__(1024) void dedup_rows(const int* __restrict__ q_idx,
                                                   const int* __restrict__ a_idx,
                                                   int* __restrict__ rank,
                                                   int* __restrict__ rows,
                                                   int* __restrict__ muniq) {
  __shared__ unsigned bm[256];
  __shared__ int cnt[1024];
  __shared__ int total;
  const int tid = threadIdx.x;
  if (tid < 256) bm[tid] = 0u;
  __syncthreads();
  for (int i = tid; i < BB * LL; i += 1024) {
    int q = q_idx[i];
    atomicOr(&bm[q >> 5], 1u << (q & 31));
  }
  for (int i = tid; i < BB * LL; i += 1024) {
    int a = a_idx[i];
    atomicOr(&bm[a >> 5], 1u << (a & 31));
  }
  __syncthreads();
  const unsigned w = bm[tid >> 2];
  const unsigned byte = (w >> ((tid & 3) * 8)) & 0xffu;
  const int myc = __popc(byte);
  cnt[tid] = myc;
  __syncthreads();
  for (int off = 1; off < 1024; off <<= 1) {
    int v = (tid >= off) ? cnt[tid - off] : 0;
    __syncthreads();
    cnt[tid] += v;
    __syncthreads();
  }
  if (tid == 1023) total = cnt[1023];
  int base = cnt[tid] - myc;
#pragma unroll
  for (int j = 0; j < 8; ++j) {
    int n = tid * 8 + j;
    int bit = (byte >> j) & 1;
    rank[n] = base;
    if (bit) rows[base++] = n;
  }
  __syncthreads();
  if (tid == 0) *muniq = total;
  if (tid < 64) rows[total + tid] = 0;
}

// ---------------------------------------------------------------- layer1 compact: C = adj[rows] @ emb (bf16 MFMA)
__global__ __launch_bounds__(512, 6) void gemm_layer1c(const float* __restrict__ adj,
                                                       const u16* __restrict__ embT,
                                                       const int* __restrict__ rows,
                                                       const int* __restrict__ muniq,
                                                       float* __restrict__ parts) {
  __shared__ __align__(16) float As[64 * 64];  // 16 KB, 16-granule swizzle ^(row&15)
  __shared__ __align__(16) u16 Bs[256 * 64];   // 32 KB, 8-granule swizzle ^(row&7)
  const int tid = threadIdx.x;
  const int lane = tid & 63, wid = tid >> 6;
  const int wm = wid >> 2, wn = wid & 3;
  const int wg = blockIdx.x;
  const int sk = wg & 7;
  const int mt = wg >> 3;
  const int m0 = mt * 64;
  const int M = *muniq;
  if (m0 >= M) return;
  const int kbeg = sk * KCH;

  f32x4 acc[2][4];
  const f32x4 zf = {0.f, 0.f, 0.f, 0.f};
#pragma unroll
  for (int i = 0; i < 2; ++i)
#pragma unroll
    for (int j = 0; j < 4; ++j) acc[i][j] = zf;

  int aRowLoc[2], aGsrc[2];
  const float* aSrc[2];
#pragma unroll
  for (int j = 0; j < 2; ++j) {
    int t = wid * 2 + j;
    aRowLoc[j] = t * 4 + (lane >> 4);
    aGsrc[j] = (lane & 15) ^ (aRowLoc[j] & 15);
    int grow = rows[m0 + aRowLoc[j]];
    aSrc[j] = adj + (size_t)grow * NN + kbeg + aGsrc[j] * 4;
  }
  const u16* bSrc[4];
#pragma unroll
  for (int j = 0; j < 4; ++j) {
    int t = wid * 4 + j;
    int rowB = t * 8 + (lane >> 3);
    int g = (lane & 7) ^ (rowB & 7);
    bSrc[j] = embT + (size_t)rowB * NN + kbeg + g * 8;
  }

  for (int s = 0; s < STEPS1; ++s) {
    const int ks = s * 64;
#pragma unroll
    for (int j = 0; j < 2; ++j)
      gld16(aSrc[j] + ks, (void*)&As[(wid * 2 + j) * 256]);
#pragma unroll
    for (int j = 0; j < 4; ++j)
      gld16(bSrc[j] + ks, (void*)&Bs[(wid * 4 + j) * 512]);
    __syncthreads();
#pragma unroll
    for (int kk = 0; kk < 64; kk += 32) {
      bf16x8 af[2], bfr[4];
      const int g0 = (kk >> 2) + ((lane >> 4) << 1);
#pragma unroll
      for (int mi = 0; mi < 2; ++mi) {
        int row = wm * 32 + mi * 16 + (lane & 15);
        f32x4 p0 = *reinterpret_cast<const f32x4*>(&As[row * 64 + ((g0 ^ (row & 15)) << 2)]);
        f32x4 p1 = *reinterpret_cast<const f32x4*>(&As[row * 64 + (((g0 + 1) ^ (row & 15)) << 2)]);
        af[mi] = pack8(p0, p1);
      }
      const int gb = (kk >> 3) + (lane >> 4);
#pragma unroll
      for (int ni = 0; ni < 4; ++ni) {
        int row = wn * 64 + ni * 16 + (lane & 15);
        bfr[ni] = *reinterpret_cast<const bf16x8*>(&Bs[row * 64 + ((gb ^ (row & 7)) << 3)]);
      }
#pragma unroll
      for (int mi = 0; mi < 2; ++mi)
#pragma unroll
        for (int ni = 0; ni < 4; ++ni)
          acc[mi][ni] = __builtin_amdgcn_mfma_f32_16x16x32_bf16(af[mi], bfr[ni], acc[mi][ni], 0, 0, 0);
    }
    __syncthreads();
  }

  float* outp = parts + (size_t)sk * ((size_t)NN * HH);
  const int r0 = (lane >> 4) << 2;
  const int coln = wn * 64 + (lane & 15);
#pragma unroll
  for (int mi = 0; mi < 2; ++mi)
#pragma unroll
    for (int ni = 0; ni < 4; ++ni)
#pragma unroll
      for (int r = 0; r < 4; ++r)
        outp[(size_t)(m0 + wm * 32 + mi * 16 + r0 + r) * HH + coln + ni * 16] = acc[mi][ni][r];
}

// ---------------------------------------------------------------- gather: bf16 Q/A rows = sum of split-K parts
__global__ __launch_bounds__(256) void gather_qa(const float* __restrict__ parts,
                                                 const int* __restrict__ q_idx,
                                                 const int* __restrict__ a_idx,
                                                 const int* __restrict__ rank,
                                                 u16* __restrict__ Qbf, u16* __restrict__ Abf) {
  const int rb = blockIdx.x;
  const bool isA = rb >= BB * LL;
  const int r = isA ? rb - BB * LL : rb;
  const int idx = (isA ? a_idx : q_idx)[r];
  const int cidx = rank[idx];
  const int tid = threadIdx.x;
  float s = 0.f;
#pragma unroll
  for (int p = 0; p < SPLITK; ++p)
    s += parts[(size_t)p * ((size_t)NN * HH) + (size_t)cidx * HH + tid];
  (isA ? Abf : Qbf)[(size_t)r * HH + tid] = f2bf_rne(s);
}

// ---------------------------------------------------------------- fused attention: score MFMA + row/col softmax
// one block per b. LDS: Qs 64K + As 64K; sc (f32 [128][132]) overlays (post-MFMA).
__global__ __launch_bounds__(512) void attn_fused(const u16* __restrict__ Qbf,
                                                  const u16* __restrict__ Abf,
                                                  u16* __restrict__ wqbf,
                                                  u16* __restrict__ watbf) {
  __shared__ __align__(16) char lraw[131072];
  u16* Qs = (u16*)lraw;
  u16* As = (u16*)(lraw + 65536);
  float* sc = (float*)lraw;               // overlays Qs+As head after MFMA done
  const int b = blockIdx.x;
  const int tid = threadIdx.x;
  const int lane = tid & 63, wid = tid >> 6;
  const int wm = wid >> 2, wn = wid & 3;

  const u16* qsrc = Qbf + (size_t)b * (LL * HH);
  const u16* asrc = Abf + (size_t)b * (LL * HH);
#pragma unroll
  for (int i = 0; i < 8; ++i) {
    int gf = i * 512 + tid;               // 4096 granules (128 rows x 32)
    int l = gf >> 5, g = gf & 31;
    int gp = g ^ (l & 7);
    *reinterpret_cast<bf16x8*>(&Qs[l * 256 + gp * 8]) = *reinterpret_cast<const bf16x8*>(qsrc + l * 256 + g * 8);
    *reinterpret_cast<bf16x8*>(&As[l * 256 + gp * 8]) = *reinterpret_cast<const bf16x8*>(asrc + l * 256 + g * 8);
  }
  __syncthreads();

  f32x4 acc[4][2];
  const f32x4 zf = {0.f, 0.f, 0.f, 0.f};
#pragma unroll
  for (int i = 0; i < 4; ++i)
#pragma unroll
    for (int j = 0; j < 2; ++j) acc[i][j] = zf;

#pragma unroll
  for (int ks = 0; ks < 8; ++ks) {
    bf16x8 af[4], bfr[2];
#pragma unroll
    for (int mi = 0; mi < 4; ++mi) {
      int row = wm * 64 + mi * 16 + (lane & 15);
      int g = ks * 4 + (lane >> 4);
      af[mi] = *reinterpret_cast<const bf16x8*>(&Qs[row * 256 + (g ^ (row & 7)) * 8]);
    }
#pragma unroll
    for (int ni = 0; ni < 2; ++ni) {
      int row = wn * 32 + ni * 16 + (lane & 15);
      int g = ks * 4 + (lane >> 4);
      bfr[ni] = *reinterpret_cast<const bf16x8*>(&As[row * 256 + (g ^ (row & 7)) * 8]);
    }
#pragma unroll
    for (int mi = 0; mi < 4; ++mi)
#pragma unroll
      for (int ni = 0; ni < 2; ++ni)
        acc[mi][ni] = __builtin_amdgcn_mfma_f32_16x16x32_bf16(af[mi], bfr[ni], acc[mi][ni], 0, 0, 0);
  }
  __syncthreads();   // Qs/As dead; sc may overlay

  const int r0 = (lane >> 4) << 2;
#pragma unroll
  for (int mi = 0; mi < 4; ++mi)
#pragma unroll
    for (int ni = 0; ni < 2; ++ni) {
      int m = wn * 32 + ni * 16 + (lane & 15);
#pragma unroll
      for (int r = 0; r < 4; ++r) {
        int l = wm * 64 + mi * 16 + r0 + r;
        sc[l * 132 + m] = acc[mi][ni][r];
      }
    }
  __syncthreads();

  // row softmax -> wqbf[l][m]
  {
    const int l = tid >> 2, j = tid & 3;
    const int base = l * 132 + j * 32;
    float mx = -3.4e38f;
#pragma unroll 8
    for (int c = 0; c < 32; ++c) mx = fmaxf(mx, sc[base + c]);
    mx = fmaxf(mx, __shfl_xor(mx, 1));
    mx = fmaxf(mx, __shfl_xor(mx, 2));
    float sum = 0.f;
#pragma unroll 8
    for (int c = 0; c < 32; ++c) sum += expf(sc[base + c] - mx);
    sum += __shfl_xor(sum, 1);
    sum += __shfl_xor(sum, 2);
    float inv = 1.f / sum;
    u16* o = wqbf + (size_t)b * (LL * LL) + l * 128 + j * 32;
#pragma unroll 8
    for (int c = 0; c < 32; ++c) o[c] = f2bf_rne(expf(sc[base + c] - mx) * inv);
  }
  // col softmax -> watbf[m][l]
  {
    const int m = tid >> 2, j = tid & 3;
    float mx = -3.4e38f;
#pragma unroll 8
    for (int r = 0; r < 32; ++r) mx = fmaxf(mx, sc[(j * 32 + r) * 132 + m]);
    mx = fmaxf(mx, __shfl_xor(mx, 1));
    mx = fmaxf(mx, __shfl_xor(mx, 2));
    float sum = 0.f;
#pragma unroll 8
    for (int r = 0; r < 32; ++r) sum += expf(sc[(j * 32 + r) * 132 + m] - mx);
    sum += __shfl_xor(sum, 1);
    sum += __shfl_xor(sum, 2);
    float inv = 1.f / sum;
    u16* o = watbf + (size_t)b * (LL * LL) + m * 128 + j * 32;
#pragma unroll 8
    for (int r = 0; r < 32; ++r) o[r] = f2bf_rne(expf(sc[(j * 32 + r) * 132 + m] - mx) * inv);
  }
}

// ---------------------------------------------------------------- align via MFMA: E = w @ src; tq/ta -> Tbf
// grid 64 (side x b). LDS: wsh 32K (swizzled) + srcT [256][140] transposed (padded).
__global__ __launch_bounds__(512) void align_mfma(const u16* __restrict__ wqbf,
                                                  const u16* __restrict__ watbf,
                                                  const u16* __restrict__ Qbf,
                                                  const u16* __restrict__ Abf,
                                                  u16* __restrict__ Tbf) {
  __shared__ __align__(16) u16 wsh[128 * 128];
  __shared__ __align__(16) u16 srcT[256 * 140];
  const int bid = blockIdx.x;
  const int side = bid >> 5, b = bid & 31;
  const int tid = threadIdx.x;
  const int lane = tid & 63, wid = tid >> 6;
  const int wm = wid >> 2, wn = wid & 3;

  const u16* wsrc = (side ? watbf : wqbf) + (size_t)b * (LL * LL);
  const u16* ssrc = (side ? Qbf : Abf) + (size_t)b * (LL * HH);
  const u16* msrc = (side ? Abf : Qbf) + (size_t)b * (LL * HH);

#pragma unroll
  for (int i = 0; i < 4; ++i) {
    int gf = i * 512 + tid;               // 2048 granules (128 rows x 16)
    int row = gf >> 4, g = gf & 15;
    int gp = g ^ (row & 7);
    *reinterpret_cast<bf16x8*>(&wsh[row * 128 + gp * 8]) = *reinterpret_cast<const bf16x8*>(wsrc + row * 128 + g * 8);
  }
#pragma unroll
  for (int i = 0; i < 8; ++i) {
    int gf = i * 512 + tid;               // 4096 vec8 (128 j x 32 g)
    int j = gf >> 5, g = gf & 31;
    bf16x8 v = *reinterpret_cast<const bf16x8*>(ssrc + j * 256 + g * 8);
#pragma unroll
    for (int e = 0; e < 8; ++e) srcT[(g * 8 + e) * 140 + j] = (u16)v[e];
  }
  __syncthreads();

  f32x4 acc[4][4];
  const f32x4 zf = {0.f, 0.f, 0.f, 0.f};
#pragma unroll
  for (int i = 0; i < 4; ++i)
#pragma unroll
    for (int j = 0; j < 4; ++j) acc[i][j] = zf;

#pragma unroll
  for (int ks = 0; ks < 4; ++ks) {
    bf16x8 af[4], bfr[4];
#pragma unroll
    for (int mi = 0; mi < 4; ++mi) {
      int row = wm * 64 + mi * 16 + (lane & 15);
      int g = ks * 4 + (lane >> 4);
      af[mi] = *reinterpret_cast<const bf16x8*>(&wsh[row * 128 + (g ^ (row & 7)) * 8]);
    }
#pragma unroll
    for (int ni = 0; ni < 4; ++ni) {
      int h = wn * 64 + ni * 16 + (lane & 15);
      int k = ks * 32 + ((lane >> 4) << 3);
      bfr[ni] = *reinterpret_cast<const bf16x8*>(&srcT[h * 140 + k]);
    }
#pragma unroll
    for (int mi = 0; mi < 4; ++mi)
#pragma unroll
      for (int ni = 0; ni < 4; ++ni)
        acc[mi][ni] = __builtin_amdgcn_mfma_f32_16x16x32_bf16(af[mi], bfr[ni], acc[mi][ni], 0, 0, 0);
  }

  u16* outp = Tbf + (size_t)(side * 4096 + b * 128) * 512;
  const int r0 = (lane >> 4) << 2;
#pragma unroll
  for (int mi = 0; mi < 4; ++mi)
#pragma unroll
    for (int ni = 0; ni < 4; ++ni) {
      int h = wn * 64 + ni * 16 + (lane & 15);
#pragma unroll
      for (int r = 0; r < 4; ++r) {
        int i2 = wm * 64 + mi * 16 + r0 + r;
        float mv = bf2f(msrc[(size_t)i2 * HH + h]);
        float e = acc[mi][ni][r];
        float d = mv - e;
        outp[(size_t)i2 * 512 + h] = f2bf_rne(d * d);
        outp[(size_t)i2 * 512 + 256 + h] = f2bf_rne(mv * e);
      }
    }
}

// ---------------------------------------------------------------- Wcat bf16 [1024][512]
__global__ __launch_bounds__(256) void prep_wcat(const float* __restrict__ w0,
                                                 const float* __restrict__ w1,
                                                 const float* __restrict__ w2,
                                                 const float* __restrict__ w3,
                                                 u16* __restrict__ Wcat) {
  const int kr = blockIdx.x;
  const int tid = threadIdx.x;
  u16* out = Wcat + (size_t)kr * 512;
  if (kr >= KK * 10) {
    out[tid] = 0;
    out[tid + 256] = 0;
    return;
  }
  const int k = kr / 10, s = kr % 10;
  const float* w;
  int r, fs;
  if (s < 1)      { w = w0; r = s;     fs = 1; }
  else if (s < 3) { w = w1; r = s - 1; fs = 2; }
  else if (s < 6) { w = w2; r = s - 3; fs = 3; }
  else            { w = w3; r = s - 6; fs = 4; }
  const float* src = w + ((size_t)k * fs + r) * 522 + 5;
  out[tid] = f2bf_rne(src[tid]);
  out[tid + 256] = f2bf_rne(src[tid + 256]);
}

// ---------------------------------------------------------------- conv GEMM: D[8192][1024] = Tbf @ Wcat^T
__global__ __launch_bounds__(512, 4) void gemm_conv(const u16* __restrict__ Tbf,
                                                    const u16* __restrict__ Wcat,
                                                    float* __restrict__ D) {
  __shared__ __align__(16) u16 As[128 * 64];
  __shared__ __align__(16) u16 Bs[256 * 64];
  const int tid = threadIdx.x;
  const int lane = tid & 63, wid = tid >> 6;
  const int wm = wid >> 2, wn = wid & 3;
  const int m0 = blockIdx.x * 128;
  const int n0 = blockIdx.y * 256;

  f32x4 acc[4][4];
  const f32x4 zf = {0.f, 0.f, 0.f, 0.f};
#pragma unroll
  for (int i = 0; i < 4; ++i)
#pragma unroll
    for (int j = 0; j < 4; ++j) acc[i][j] = zf;

  const int browL = (lane >> 3);
  const int bkL = (lane & 7) << 3;

  for (int s = 0; s < STEPS2; ++s) {
    const int ks = s * 64;
#pragma unroll
    for (int j = 0; j < 2; ++j) {
      int rowA = (wid << 4) + (j << 3) + browL;
      int kA = bkL ^ ((rowA & 7) << 3);
      gld16(Tbf + (size_t)(m0 + rowA) * 512 + ks + kA, (void*)&As[(wid * 2 + j) * 512]);
    }
#pragma unroll
    for (int j = 0; j < 4; ++j) {
      int rowB = (wid << 5) + (j << 3) + browL;
      int kB = bkL ^ ((rowB & 7) << 3);
      gld16(Wcat + (size_t)(n0 + rowB) * 512 + ks + kB, (void*)&Bs[(wid * 4 + j) * 512]);
    }
    __syncthreads();
#pragma unroll
    for (int kk = 0; kk < 64; kk += 32) {
      const int krow = kk + ((lane >> 4) << 3);
      bf16x8 af[4], bfr[4];
#pragma unroll
      for (int mi = 0; mi < 4; ++mi) {
        int row = wm * 64 + mi * 16 + (lane & 15);
        af[mi] = *reinterpret_cast<const bf16x8*>(&As[row * 64 + (krow ^ ((row & 7) << 3))]);
      }
#pragma unroll
      for (int ni = 0; ni < 4; ++ni) {
        int row = wn * 64 + ni * 16 + (lane & 15);
        bfr[ni] = *reinterpret_cast<const bf16x8*>(&Bs[row * 64 + (krow ^ ((row & 7) << 3))]);
      }
#pragma unroll
      for (int mi = 0; mi < 4; ++mi)
#pragma unroll
        for (int ni = 0; ni < 4; ++ni)
          acc[mi][ni] = __builtin_amdgcn_mfma_f32_16x16x32_bf16(af[mi], bfr[ni], acc[mi][ni], 0, 0, 0);
    }
    __syncthreads();
  }

  const int r0 = (lane >> 4) << 2;
  const int coln = n0 + wn * 64 + (lane & 15);
#pragma unroll
  for (int mi = 0; mi < 4; ++mi)
#pragma unroll
    for (int ni = 0; ni < 4; ++ni)
#pragma unroll
      for (int r = 0; r < 4; ++r)
        D[(size_t)(m0 + wm * 64 + mi * 16 + r0 + r) * NPAD + coln + ni * 16] = acc[mi][ni][r];
}

// ---------------------------------------------------------------- shift-sum + bias + relu + maxpool -> re[32][800]
__global__ __launch_bounds__(256) void reduce_conv(const float* __restrict__ D,
                                                   const float* __restrict__ b0,
                                                   const float* __restrict__ b1,
                                                   const float* __restrict__ b2,
                                                   const float* __restrict__ b3,
                                                   float* __restrict__ re) {
  __shared__ float tile[128][101];
  const int pair = blockIdx.y;
  const int sel = pair >> 5, b = pair & 31;
  const int kc = blockIdx.x;
  const int tid = threadIdx.x;
  const int rowbase = sel * (BB * LL) + b * LL;
  const int c0 = kc * 100;
  for (int idx = tid; idx < 12800; idx += 256) {
    int r = idx / 100, c = idx - r * 100;
    tile[r][c] = D[(size_t)(rowbase + r) * NPAD + c0 + c];
  }
  __syncthreads();
  const int wid = tid >> 6, lane = tid & 63;
  const int offt[4] = {0, 1, 3, 6};
  const int fst[4] = {1, 2, 3, 4};
  for (int o = wid; o < 40; o += 4) {
    const int kk = o >> 2, f = o & 3;
    const int fs = fst[f], off = offt[f];
    const int kg = kc * 10 + kk;
    const float bias = (f == 0 ? b0 : f == 1 ? b1 : f == 2 ? b2 : b3)[kg];
    const int col = kk * 10 + off;
    const int outh = 139 - fs;
    float best = 0.f;
    for (int i = lane; i < outh; i += 64) {
      float s = bias;
#pragma unroll 4
      for (int r = 0; r < 4; ++r) {
        if (r < fs) {
          int j = i + r - 5;
          if (j >= 0 && j < LL) s += tile[j][col + r];
        }
      }
      best = fmaxf(best, s);
    }
    best = fmaxf(best, 0.f);
#pragma unroll
    for (int d = 32; d; d >>= 1) best = fmaxf(best, __shfl_xor(best, d));
    if (lane == 0) re[(size_t)b * 800 + sel * 400 + f * 100 + kg] = best;
  }
}

// ---------------------------------------------------------------- dense + log_softmax -> out[32][2]
__global__ __launch_bounds__(64) void dense_logsm(const float* __restrict__ re,
                                                  const float* __restrict__ dw,
                                                  const float* __restrict__ db,
                                                  float* __restrict__ out) {
  const int b = blockIdx.x;
  const int lane = threadIdx.x;
  const float* r = re + (size_t)b * 800;
  float a0 = 0.f, a1 = 0.f;
  for (int j = lane; j < 800; j += 64) {
    float rv = r[j];
    a0 += rv * dw[j * 2];
    a1 += rv * dw[j * 2 + 1];
  }
#pragma unroll
  for (int d = 32; d; d >>= 1) {
    a0 += __shfl_xor(a0, d);
    a1 += __shfl_xor(a1, d);
  }
  if (lane == 0) {
    a0 += db[0];
    a1 += db[1];
    float mx = fmaxf(a0, a1);
    float lse = mx + logf(expf(a0 - mx) + expf(a1 - mx));
    out[b * 2] = a0 - lse;
    out[b * 2 + 1] = a1 - lse;
  }
}

// ---------------------------------------------------------------- workspace layout (bytes)
static const size_t OFF_PARTS = 0;                         // 8 * 8192*256 f32 = 67,108,864
static const size_t OFF_D     = 0;                         // alias (parts dead by conv time)
static const size_t OFF_QBF   = 67108864;                  // bf16 [4096][256] = 2 MB
static const size_t OFF_ABF   = OFF_QBF + 2097152;
static const size_t OFF_WQB   = OFF_ABF + 2097152;         // bf16 [32][128][128] = 1 MB
static const size_t OFF_WAB   = OFF_WQB + 1048576;
static const size_t OFF_RE    = OFF_WAB + 1048576;
static const size_t OFF_TBF   = OFF_RE + 102400;           // bf16 [8192][512] = 8 MB
static const size_t OFF_WCAT  = OFF_TBF + 8388608;
static const size_t OFF_EMBT  = OFF_WCAT + 1048576;
static const size_t OFF_RANK  = OFF_EMBT + 4194304;
static const size_t OFF_ROWS  = OFF_RANK + 32768;
static const size_t OFF_MUNIQ = OFF_ROWS + 33024;

extern "C" void kernel_launch(void* const* d_in, const int* in_sizes, int n_in,
                              void* d_out, int out_size, void* d_ws, size_t ws_size,
                              hipStream_t stream) {
  (void)in_sizes; (void)n_in; (void)out_size; (void)ws_size;
  const float* adj  = (const float*)d_in[0];
  const float* emb  = (const float*)d_in[1];
  const int* q_idx  = (const int*)d_in[2];
  const int* a_idx  = (const int*)d_in[3];
  const float* cw0 = (const float*)d_in[4];
  const float* cb0 = (const float*)d_in[5];
  const float* cw1 = (const float*)d_in[6];
  const float* cb1 = (const float*)d_in[7];
  const float* cw2 = (const float*)d_in[8];
  const float* cb2 = (const float*)d_in[9];
  const float* cw3 = (const float*)d_in[10];
  const float* cb3 = (const float*)d_in[11];
  const float* dw = (const float*)d_in[12];
  const float* db = (const float*)d_in[13];
  float* out = (float*)d_out;

  char* ws = (char*)d_ws;
  float* parts = (float*)(ws + OFF_PARTS);
  float* Dbuf  = (float*)(ws + OFF_D);
  u16* Qbf     = (u16*)(ws + OFF_QBF);
  u16* Abf     = (u16*)(ws + OFF_ABF);
  u16* wqbf    = (u16*)(ws + OFF_WQB);
  u16* watbf   = (u16*)(ws + OFF_WAB);
  float* re    = (float*)(ws + OFF_RE);
  u16* Tbf     = (u16*)(ws + OFF_TBF);
  u16* Wcat    = (u16*)(ws + OFF_WCAT);
  u16* embT    = (u16*)(ws + OFF_EMBT);
  int* rank    = (int*)(ws + OFF_RANK);
  int* rows    = (int*)(ws + OFF_ROWS);
  int* muniq   = (int*)(ws + OFF_MUNIQ);

  convert_embT<<<dim3(128, 4), 256, 0, stream>>>(emb, embT);
  dedup_rows<<<1, 1024, 0, stream>>>(q_idx, a_idx, rank, rows, muniq);
  prep_wcat<<<1024, 256, 0, stream>>>(cw0, cw1, cw2, cw3, Wcat);
  gemm_layer1c<<<128 * SPLITK, 512, 0, stream>>>(adj, embT, rows, muniq, parts);
  gather_qa<<<2 * BB * LL, 256, 0, stream>>>(parts, q_idx, a_idx, rank, Qbf, Abf);
  attn_fused<<<BB, 512, 0, stream>>>(Qbf, Abf, wqbf, watbf);
  align_mfma<<<64, 512, 0, stream>>>(wqbf, watbf, Qbf, Abf, Tbf);
  gemm_conv<<<dim3(64, 4), 512, 0, stream>>>(Tbf, Wcat, Dbuf);
  reduce_conv<<<dim3(10, 64), 256, 0, stream>>>(Dbuf, cb0, cb1, cb2, cb3, re);
  dense_logsm<<<BB, 64, 0, stream>>>(re, dw, db, out);
}